// Round 1
// baseline (252.637 us; speedup 1.0000x reference)
//
#include <hip/hip_runtime.h>
#include <math.h>

// Problem constants (B,C,T,H,W)=(4,3,12,256,256), CH0=32
#define HW_    65536
#define THW_   786432      // T*H*W
#define N1_    3145728.0   // B*T*H*W  (bn0 / rt / tt element count)
#define N3_    262144.0    // B*H*W    (per-o min/max count)
#define NPIXI  262144      // B*H*W

// Ricker (K=5, a=1.25) and ramp weights, precomputed on host side of math
__device__ __constant__ float PW_[5] = {-0.33647654f, 0.20279402f, 0.77575913f, 0.20279402f, -0.33647654f};
__device__ __constant__ float RW_[5] = {-0.2f, -0.1f, 0.0f, 0.1f, 0.2f};

__device__ __forceinline__ float wred64(float v) {
#pragma unroll
  for (int m = 32; m > 0; m >>= 1) v += __shfl_xor(v, m, 64);
  return v;
}

__device__ __forceinline__ float fsilu(float y) {
  float e = __expf(-y);                       // v_exp based fast exp
  return y * __builtin_amdgcn_rcpf(1.0f + e); // y * sigmoid(y); inf -> 0 handled
}

// ws layout: doubles dws[0..415] accumulators; float consts at byte 4096
//  dws[0..2]  = sum x_c ; dws[3..8] = sum x_c*x_c' (00,01,02,11,12,22)
//  dws[9..12] = S_rt, SS_rt, S_tt, SS_tt
//  dws[16+o], [48+o], [80+o], [112+o] = S_min, SS_min, S_max, SS_max per o
//  dws[160 + 2*(b*32+o) + {0,1}] = S_enc, SS_enc per instance-norm slice
// cf[0..95]=w0eff, [96..127]=beta0, [128..131]=a_rt,b_rt,a_tt,b_tt,
// [132+o]=a_min,[164+o]=b_min,[196+o]=a_max,[228+o]=b_max,[260+o]=a_mean,[292+o]=b_mean

__global__ void k_init(double* dws) {
  int i = blockIdx.x * 256 + threadIdx.x;
  if (i < 416) dws[i] = 0.0;
}

__global__ __launch_bounds__(256) void k_xstats(const float* __restrict__ x, double* __restrict__ dws) {
  const int v = blockIdx.x * 256 + threadIdx.x; // float4 index in [0,196608)
  const float4* x4 = (const float4*)x;
  float s0 = 0, s1 = 0, s2 = 0, p00 = 0, p01 = 0, p02 = 0, p11 = 0, p12 = 0, p22 = 0;
#pragma unroll
  for (int b = 0; b < 4; b++) {
    float4 a0 = x4[(size_t)(b * 3 + 0) * 196608 + v];
    float4 a1 = x4[(size_t)(b * 3 + 1) * 196608 + v];
    float4 a2 = x4[(size_t)(b * 3 + 2) * 196608 + v];
    s0 += a0.x + a0.y + a0.z + a0.w;
    s1 += a1.x + a1.y + a1.z + a1.w;
    s2 += a2.x + a2.y + a2.z + a2.w;
    p00 += a0.x * a0.x + a0.y * a0.y + a0.z * a0.z + a0.w * a0.w;
    p11 += a1.x * a1.x + a1.y * a1.y + a1.z * a1.z + a1.w * a1.w;
    p22 += a2.x * a2.x + a2.y * a2.y + a2.z * a2.z + a2.w * a2.w;
    p01 += a0.x * a1.x + a0.y * a1.y + a0.z * a1.z + a0.w * a1.w;
    p02 += a0.x * a2.x + a0.y * a2.y + a0.z * a2.z + a0.w * a2.w;
    p12 += a1.x * a2.x + a1.y * a2.y + a1.z * a2.z + a1.w * a2.w;
  }
  float vals[9] = {s0, s1, s2, p00, p01, p02, p11, p12, p22};
  __shared__ float red[4][9];
  int wave = threadIdx.x >> 6, lane = threadIdx.x & 63;
#pragma unroll
  for (int q = 0; q < 9; q++) vals[q] = wred64(vals[q]);
  if (lane == 0) {
#pragma unroll
    for (int q = 0; q < 9; q++) red[wave][q] = vals[q];
  }
  __syncthreads();
  if (threadIdx.x < 9) {
    double t = (double)red[0][threadIdx.x] + red[1][threadIdx.x] + red[2][threadIdx.x] + red[3][threadIdx.x];
    atomicAdd(&dws[threadIdx.x], t);
  }
}

__global__ void k_fin0(const double* __restrict__ dws, const float* __restrict__ w0,
                       const float* __restrict__ g0, const float* __restrict__ b0, float* __restrict__ cf) {
  int o = threadIdx.x;
  if (o >= 32) return;
  double mu0 = dws[0] / N1_, mu1 = dws[1] / N1_, mu2 = dws[2] / N1_;
  double M00 = dws[3] / N1_, M01 = dws[4] / N1_, M02 = dws[5] / N1_;
  double M11 = dws[6] / N1_, M12 = dws[7] / N1_, M22 = dws[8] / N1_;
  double c0 = w0[o * 3 + 0], c1 = w0[o * 3 + 1], c2 = w0[o * 3 + 2];
  double Ey = c0 * mu0 + c1 * mu1 + c2 * mu2;
  double Ey2 = c0 * c0 * M00 + c1 * c1 * M11 + c2 * c2 * M22 +
               2.0 * (c0 * c1 * M01 + c0 * c2 * M02 + c1 * c2 * M12);
  double var = Ey2 - Ey * Ey;
  double alpha = (double)g0[o] / sqrt(var + 1e-5);
  cf[o * 3 + 0] = (float)(alpha * c0);
  cf[o * 3 + 1] = (float)(alpha * c1);
  cf[o * 3 + 2] = (float)(alpha * c2);
  cf[96 + o] = (float)((double)b0[o] - Ey * alpha);
}

// Shared per-pixel prelude: load x column + temporal-conv tt_pre
#define PIXEL_PRELUDE()                                                      \
  const int pix = blockIdx.x * 256 + threadIdx.x;                            \
  const int b = pix >> 16, hw = pix & 65535;                                 \
  const float* xp = x + (size_t)b * 3 * THW_ + hw;                           \
  float xv[3][12];                                                           \
  _Pragma("unroll") for (int c = 0; c < 3; c++)                              \
      _Pragma("unroll") for (int t = 0; t < 12; t++)                         \
          xv[c][t] = xp[(size_t)(c * 12 + t) * HW_];                         \
  float wt[3] = {wtt[0], wtt[1], wtt[2]};                                    \
  float ttp[12];                                                             \
  _Pragma("unroll") for (int t = 0; t < 12; t++) {                           \
    float acc = 0.f;                                                         \
    _Pragma("unroll") for (int c = 0; c < 3; c++) {                          \
      float pk = 0.f, sl = 0.f;                                              \
      _Pragma("unroll") for (int j = 0; j < 5; j++) {                        \
        int tj = t - 2 + j;                                                  \
        if (tj >= 0 && tj < 12) {                                            \
          pk = fmaf(PW_[j], xv[c][tj], pk);                                  \
          sl = fmaf(RW_[j], xv[c][tj], sl);                                  \
        }                                                                    \
      }                                                                      \
      acc = fmaf(wt[c], pk + fabsf(sl), acc);                                \
    }                                                                        \
    ttp[t] = acc;                                                            \
  }

__global__ __launch_bounds__(256) void k_passB(const float* __restrict__ x, const float* __restrict__ wrt,
                                               const float* __restrict__ wtt, const float* __restrict__ cf,
                                               double* __restrict__ dws) {
  PIXEL_PRELUDE();
  float rt_t[12];
#pragma unroll
  for (int t = 0; t < 12; t++) rt_t[t] = 0.f;
  __shared__ float red[4][132];
  int wave = threadIdx.x >> 6, lane = threadIdx.x & 63;
#pragma unroll
  for (int o = 0; o < 32; o++) {
    float a0 = cf[o * 3], a1 = cf[o * 3 + 1], a2 = cf[o * 3 + 2];
    float bet = cf[96 + o], wo = wrt[o];
    float mn = 3.4e38f, mx = -3.4e38f;
#pragma unroll
    for (int t = 0; t < 12; t++) {
      float y = fmaf(a0, xv[0][t], fmaf(a1, xv[1][t], fmaf(a2, xv[2][t], bet)));
      float h = fsilu(y);
      mn = fminf(mn, h);
      mx = fmaxf(mx, h);
      rt_t[t] = fmaf(wo, h, rt_t[t]);
    }
    float q0 = wred64(mn), q1 = wred64(mn * mn), q2 = wred64(mx), q3 = wred64(mx * mx);
    if (lane == 0) {
      red[wave][o * 4 + 0] = q0;
      red[wave][o * 4 + 1] = q1;
      red[wave][o * 4 + 2] = q2;
      red[wave][o * 4 + 3] = q3;
    }
  }
  float srt = 0, ssrt = 0, stt = 0, sstt = 0;
#pragma unroll
  for (int t = 0; t < 12; t++) {
    srt += rt_t[t];
    ssrt = fmaf(rt_t[t], rt_t[t], ssrt);
    stt += ttp[t];
    sstt = fmaf(ttp[t], ttp[t], sstt);
  }
  srt = wred64(srt);
  ssrt = wred64(ssrt);
  stt = wred64(stt);
  sstt = wred64(sstt);
  if (lane == 0) {
    red[wave][128] = srt;
    red[wave][129] = ssrt;
    red[wave][130] = stt;
    red[wave][131] = sstt;
  }
  __syncthreads();
  int tid = threadIdx.x;
  if (tid < 132) {
    double v = (double)red[0][tid] + red[1][tid] + red[2][tid] + red[3][tid];
    int gi;
    if (tid < 128) {
      int o = tid >> 2, q = tid & 3;
      gi = 16 + q * 32 + o;
    } else {
      gi = 9 + (tid - 128);
    }
    atomicAdd(&dws[gi], v);
  }
}

__global__ void k_finB(const double* __restrict__ dws, const float* __restrict__ grt, const float* __restrict__ brt,
                       const float* __restrict__ gtt, const float* __restrict__ btt, const float* __restrict__ gmin,
                       const float* __restrict__ bmin, const float* __restrict__ gmax, const float* __restrict__ bmax,
                       const float* __restrict__ gmean, const float* __restrict__ bmean, float* __restrict__ cf) {
  int tid = threadIdx.x;
  if (tid == 32) {
    double m = dws[9] / N1_, v = dws[10] / N1_ - m * m;
    double a = (double)grt[0] / sqrt(v + 1e-5);
    cf[128] = (float)a;
    cf[129] = (float)((double)brt[0] - m * a);
    m = dws[11] / N1_;
    v = dws[12] / N1_ - m * m;
    a = (double)gtt[0] / sqrt(v + 1e-5);
    cf[130] = (float)a;
    cf[131] = (float)((double)btt[0] - m * a);
  }
  if (tid < 32) {
    double m = dws[16 + tid] / N3_, v = dws[48 + tid] / N3_ - m * m;
    double a = (double)gmin[tid] / sqrt(v + 1e-5);
    cf[132 + tid] = (float)a;
    cf[164 + tid] = (float)((double)bmin[tid] - m * a);
    double mm = dws[80 + tid] / N3_, vv = dws[112 + tid] / N3_ - mm * mm;
    a = (double)gmax[tid] / sqrt(vv + 1e-5);
    cf[196 + tid] = (float)a;
    cf[228 + tid] = (float)((double)bmax[tid] - mm * a);
    a = (double)gmean[tid] / sqrt(vv + 1e-5);
    cf[260 + tid] = (float)a;
    cf[292 + tid] = (float)((double)bmean[tid] - mm * a);
  }
}

__global__ __launch_bounds__(256) void k_passC(const float* __restrict__ x, const float* __restrict__ wrt,
                                               const float* __restrict__ wtt, const float* __restrict__ wth,
                                               const float* __restrict__ bth, const float* __restrict__ cf,
                                               double* __restrict__ dws, float* __restrict__ out) {
  PIXEL_PRELUDE();
  float rt_t[12];
#pragma unroll
  for (int t = 0; t < 12; t++) rt_t[t] = 0.f;
  float xmn[32], xmx[32];
#pragma unroll
  for (int o = 0; o < 32; o++) {
    float a0 = cf[o * 3], a1 = cf[o * 3 + 1], a2 = cf[o * 3 + 2];
    float bet = cf[96 + o], wo = wrt[o];
    float mn = 3.4e38f, mx = -3.4e38f;
#pragma unroll
    for (int t = 0; t < 12; t++) {
      float y = fmaf(a0, xv[0][t], fmaf(a1, xv[1][t], fmaf(a2, xv[2][t], bet)));
      float h = fsilu(y);
      mn = fminf(mn, h);
      mx = fmaxf(mx, h);
      rt_t[t] = fmaf(wo, h, rt_t[t]);
    }
    xmn[o] = mn;
    xmx[o] = mx;
  }
  float art = cf[128], brt_ = cf[129], att = cf[130], btt_ = cf[131];
  float rtt[12];
#pragma unroll
  for (int t = 0; t < 12; t++)
    rtt[t] = fsilu(fmaf(art, rt_t[t], brt_)) + fsilu(fmaf(att, ttp[t], btt_));
  __shared__ float red[4][64];
  int wave = threadIdx.x >> 6, lane = threadIdx.x & 63;
#pragma unroll
  for (int o = 0; o < 32; o++) {
    float tl = bth[o];
#pragma unroll
    for (int t = 0; t < 12; t++) tl = fmaf(wth[o * 12 + t], rtt[t], tl);
    float e = tl + fsilu(fmaf(cf[132 + o], xmn[o], cf[164 + o]))
                 + fsilu(fmaf(cf[196 + o], xmx[o], cf[228 + o]))
                 + fsilu(fmaf(cf[260 + o], xmx[o], cf[292 + o]));
    out[((size_t)(b * 32 + o) << 16) + hw] = e;
    float se = wred64(e), se2 = wred64(e * e);
    if (lane == 0) {
      red[wave][o * 2 + 0] = se;
      red[wave][o * 2 + 1] = se2;
    }
  }
  __syncthreads();
  int tid = threadIdx.x;
  if (tid < 64) {
    double v = (double)red[0][tid] + red[1][tid] + red[2][tid] + red[3][tid];
    int o = tid >> 1, q = tid & 1;
    atomicAdd(&dws[160 + (b * 32 + o) * 2 + q], v);
  }
}

__global__ __launch_bounds__(256) void k_inorm(const double* __restrict__ dws, float* __restrict__ out) {
  int s = blockIdx.y;
  double S = dws[160 + s * 2], SS = dws[161 + s * 2];
  double m = S / 65536.0, v = SS / 65536.0 - m * m;
  float rstd = (float)(1.0 / sqrt(v + 1e-5));
  float mf = (float)m;
  float4* p = (float4*)(out + ((size_t)s << 16));
  int i = blockIdx.x * 256 + threadIdx.x; // float4 index, 64*256=16384 covers 65536 floats
  float4 a = p[i];
  a.x = (a.x - mf) * rstd;
  a.y = (a.y - mf) * rstd;
  a.z = (a.z - mf) * rstd;
  a.w = (a.w - mf) * rstd;
  p[i] = a;
}

extern "C" void kernel_launch(void* const* d_in, const int* in_sizes, int n_in,
                              void* d_out, int out_size, void* d_ws, size_t ws_size,
                              hipStream_t stream) {
  const float* x     = (const float*)d_in[0];
  const float* w0    = (const float*)d_in[1];
  const float* g0    = (const float*)d_in[2];
  const float* b0    = (const float*)d_in[3];
  const float* wrt   = (const float*)d_in[4];
  const float* grt   = (const float*)d_in[5];
  const float* brt   = (const float*)d_in[6];
  const float* wtt   = (const float*)d_in[7];
  const float* gtt   = (const float*)d_in[8];
  const float* btt   = (const float*)d_in[9];
  const float* wth   = (const float*)d_in[10];
  const float* bth   = (const float*)d_in[11];
  const float* gmin  = (const float*)d_in[12];
  const float* bmin  = (const float*)d_in[13];
  const float* gmax  = (const float*)d_in[14];
  const float* bmax  = (const float*)d_in[15];
  const float* gmean = (const float*)d_in[16];
  const float* bmean = (const float*)d_in[17];
  double* dws = (double*)d_ws;
  float* cf = (float*)((char*)d_ws + 4096);
  float* out = (float*)d_out;

  hipLaunchKernelGGL(k_init, dim3(2), dim3(256), 0, stream, dws);
  hipLaunchKernelGGL(k_xstats, dim3(768), dim3(256), 0, stream, x, dws);
  hipLaunchKernelGGL(k_fin0, dim3(1), dim3(32), 0, stream, dws, w0, g0, b0, cf);
  hipLaunchKernelGGL(k_passB, dim3(1024), dim3(256), 0, stream, x, wrt, wtt, cf, dws);
  hipLaunchKernelGGL(k_finB, dim3(1), dim3(64), 0, stream, dws, grt, brt, gtt, btt,
                     gmin, bmin, gmax, bmax, gmean, bmean, cf);
  hipLaunchKernelGGL(k_passC, dim3(1024), dim3(256), 0, stream, x, wrt, wtt, wth, bth, cf, dws, out);
  hipLaunchKernelGGL(k_inorm, dim3(64, 128), dim3(256), 0, stream, dws, out);
}

// Round 3
// 125.225 us; speedup vs baseline: 2.0175x; 2.0175x over previous
//
#include <hip/hip_runtime.h>
#include <math.h>

// Problem constants (B,C,T,H,W)=(4,3,12,256,256), CH0=32
#define HW_    65536
#define THW_   786432      // T*H*W
#define NP     262144      // B*H*W pixels
#define N1_    3145728.0   // B*T*H*W
#define N3_    262144.0    // B*H*W

// Ricker (K=5, a=1.25) and ramp weights
__device__ __constant__ float PW_[5] = {-0.33647654f, 0.20279402f, 0.77575913f, 0.20279402f, -0.33647654f};
__device__ __constant__ float RW_[5] = {-0.2f, -0.1f, 0.0f, 0.1f, 0.2f};

typedef __fp16 fp16x2 __attribute__((ext_vector_type(2)));
union H2U { fp16x2 h; unsigned int u; };
__device__ __forceinline__ unsigned int packh(float a, float b) {
  H2U x; x.h = __builtin_amdgcn_cvt_pkrtz(a, b); return x.u;
}
__device__ __forceinline__ float2 unpackh(unsigned int v) {
  H2U x; x.u = v; return make_float2((float)x.h.x, (float)x.h.y);
}

__device__ __forceinline__ float wred64(float v) {
#pragma unroll
  for (int m = 32; m > 0; m >>= 1) v += __shfl_xor(v, m, 64);
  return v;
}

__device__ __forceinline__ float fsilu(float y) {
  float e = __expf(-y);
  return y * __builtin_amdgcn_rcpf(1.0f + e);
}

// ws layout: doubles dws[0..415] at byte 0; float cf[] at byte 4096;
//   pRT (uint, 12*NP)  at byte 8192              : lo=rt_pre fp16, hi=tt_pre fp16, plane-major [t][pixel]
//   pMM (uint, 32*NP)  at byte 8192+12*NP*4      : lo=min fp16, hi=max fp16, plane-major [o][pixel]
// dws: [0..2] sum x_c; [3..8] sum x_c*x_c'; [9..12] S_rt,SS_rt,S_tt,SS_tt;
//      [16+o],[48+o],[80+o],[112+o] S_mn,SS_mn,S_mx,SS_mx; [160+2s{,+1}] S_enc,SS_enc
// cf: [0..95] w0eff; [96..127] beta0; [128..131] a_rt,b_rt,a_tt,b_tt;
//     [132+o] a_min; [164+o] b_min; [196+o] a_max; [228+o] b_max; [260+o] a_mean; [292+o] b_mean

__global__ void k_init(double* dws) {
  int i = blockIdx.x * 256 + threadIdx.x;
  if (i < 416) dws[i] = 0.0;
}

__global__ __launch_bounds__(256) void k_xstats(const float* __restrict__ x, double* __restrict__ dws) {
  const int v = blockIdx.x * 256 + threadIdx.x; // float4 index in [0,196608)
  const float4* x4 = (const float4*)x;
  float s0 = 0, s1 = 0, s2 = 0, p00 = 0, p01 = 0, p02 = 0, p11 = 0, p12 = 0, p22 = 0;
#pragma unroll
  for (int b = 0; b < 4; b++) {
    float4 a0 = x4[(size_t)(b * 3 + 0) * 196608 + v];
    float4 a1 = x4[(size_t)(b * 3 + 1) * 196608 + v];
    float4 a2 = x4[(size_t)(b * 3 + 2) * 196608 + v];
    s0 += a0.x + a0.y + a0.z + a0.w;
    s1 += a1.x + a1.y + a1.z + a1.w;
    s2 += a2.x + a2.y + a2.z + a2.w;
    p00 += a0.x * a0.x + a0.y * a0.y + a0.z * a0.z + a0.w * a0.w;
    p11 += a1.x * a1.x + a1.y * a1.y + a1.z * a1.z + a1.w * a1.w;
    p22 += a2.x * a2.x + a2.y * a2.y + a2.z * a2.z + a2.w * a2.w;
    p01 += a0.x * a1.x + a0.y * a1.y + a0.z * a1.z + a0.w * a1.w;
    p02 += a0.x * a2.x + a0.y * a2.y + a0.z * a2.z + a0.w * a2.w;
    p12 += a1.x * a2.x + a1.y * a2.y + a1.z * a2.z + a1.w * a2.w;
  }
  float vals[9] = {s0, s1, s2, p00, p01, p02, p11, p12, p22};
  __shared__ float red[4][9];
  int wave = threadIdx.x >> 6, lane = threadIdx.x & 63;
#pragma unroll
  for (int q = 0; q < 9; q++) vals[q] = wred64(vals[q]);
  if (lane == 0) {
#pragma unroll
    for (int q = 0; q < 9; q++) red[wave][q] = vals[q];
  }
  __syncthreads();
  if (threadIdx.x < 9) {
    double t = (double)red[0][threadIdx.x] + red[1][threadIdx.x] + red[2][threadIdx.x] + red[3][threadIdx.x];
    atomicAdd(&dws[threadIdx.x], t);
  }
}

__global__ void k_fin0(const double* __restrict__ dws, const float* __restrict__ w0,
                       const float* __restrict__ g0, const float* __restrict__ b0, float* __restrict__ cf) {
  int o = threadIdx.x;
  if (o >= 32) return;
  double mu0 = dws[0] / N1_, mu1 = dws[1] / N1_, mu2 = dws[2] / N1_;
  double M00 = dws[3] / N1_, M01 = dws[4] / N1_, M02 = dws[5] / N1_;
  double M11 = dws[6] / N1_, M12 = dws[7] / N1_, M22 = dws[8] / N1_;
  double c0 = w0[o * 3 + 0], c1 = w0[o * 3 + 1], c2 = w0[o * 3 + 2];
  double Ey = c0 * mu0 + c1 * mu1 + c2 * mu2;
  double Ey2 = c0 * c0 * M00 + c1 * c1 * M11 + c2 * c2 * M22 +
               2.0 * (c0 * c1 * M01 + c0 * c2 * M02 + c1 * c2 * M12);
  double var = Ey2 - Ey * Ey;
  double alpha = (double)g0[o] / sqrt(var + 1e-5);
  cf[o * 3 + 0] = (float)(alpha * c0);
  cf[o * 3 + 1] = (float)(alpha * c1);
  cf[o * 3 + 2] = (float)(alpha * c2);
  cf[96 + o] = (float)((double)b0[o] - Ey * alpha);
}

// passB: compute h once; stream fp16 intermediates; NO reductions here.
__global__ __launch_bounds__(256) void k_passB(const float* __restrict__ x, const float* __restrict__ wrt,
                                               const float* __restrict__ wtt, const float* __restrict__ cf,
                                               unsigned int* __restrict__ pRT, unsigned int* __restrict__ pMM) {
  const int pix = blockIdx.x * 256 + threadIdx.x;
  const int b = pix >> 16, hw = pix & 65535;
  const float* xp = x + (size_t)b * 3 * THW_ + hw;
  float xv[3][12];
#pragma unroll
  for (int c = 0; c < 3; c++)
#pragma unroll
    for (int t = 0; t < 12; t++) xv[c][t] = xp[(size_t)(c * 12 + t) * HW_];
  float wt[3] = {wtt[0], wtt[1], wtt[2]};
  float ttp[12];
#pragma unroll
  for (int t = 0; t < 12; t++) {
    float acc = 0.f;
#pragma unroll
    for (int c = 0; c < 3; c++) {
      float pk = 0.f, sl = 0.f;
#pragma unroll
      for (int j = 0; j < 5; j++) {
        int tj = t - 2 + j;
        if (tj >= 0 && tj < 12) {
          pk = fmaf(PW_[j], xv[c][tj], pk);
          sl = fmaf(RW_[j], xv[c][tj], sl);
        }
      }
      acc = fmaf(wt[c], pk + fabsf(sl), acc);
    }
    ttp[t] = acc;
  }
  float rt_t[12];
#pragma unroll
  for (int t = 0; t < 12; t++) rt_t[t] = 0.f;
#pragma unroll
  for (int o = 0; o < 32; o++) {
    float a0 = cf[o * 3], a1 = cf[o * 3 + 1], a2 = cf[o * 3 + 2];
    float bet = cf[96 + o], wo = wrt[o];
    float mn = 3.4e38f, mx = -3.4e38f;
#pragma unroll
    for (int t = 0; t < 12; t++) {
      float y = fmaf(a0, xv[0][t], fmaf(a1, xv[1][t], fmaf(a2, xv[2][t], bet)));
      float h = fsilu(y);
      mn = fminf(mn, h);
      mx = fmaxf(mx, h);
      rt_t[t] = fmaf(wo, h, rt_t[t]);
    }
    pMM[o * NP + pix] = packh(mn, mx);
  }
#pragma unroll
  for (int t = 0; t < 12; t++) pRT[t * NP + pix] = packh(rt_t[t], ttp[t]);
}

// Streaming stats over the fp16 intermediate planes.
// blocks [0,96): rt/tt sums over all 12*NP entries -> dws[9..12]
// blocks [96,352): 8 blocks per o over pMM plane -> dws[16/48/80/112 + o]
__global__ __launch_bounds__(256) void k_stats(const unsigned int* __restrict__ pRT,
                                               const unsigned int* __restrict__ pMM,
                                               double* __restrict__ dws) {
  __shared__ float red[4][4];
  int bid = blockIdx.x, tid = threadIdx.x;
  float s0 = 0, s1 = 0, s2 = 0, s3 = 0;
  if (bid < 96) {
    const uint4* p = (const uint4*)pRT;
    int base = bid * 256 + tid;
#pragma unroll 4
    for (int it = 0; it < 32; it++) {
      uint4 v = p[base + it * 24576];
      float2 a = unpackh(v.x), b = unpackh(v.y), c = unpackh(v.z), d = unpackh(v.w);
      s0 += a.x + b.x + c.x + d.x;
      s1 += a.x * a.x + b.x * b.x + c.x * c.x + d.x * d.x;
      s2 += a.y + b.y + c.y + d.y;
      s3 += a.y * a.y + b.y * b.y + c.y * c.y + d.y * d.y;
    }
  } else {
    int o = (bid - 96) >> 3, sub = (bid - 96) & 7;
    const uint4* p = (const uint4*)(pMM + (size_t)o * NP);
    int base = sub * 256 + tid;
#pragma unroll 4
    for (int it = 0; it < 32; it++) {
      uint4 v = p[base + it * 2048];
      float2 a = unpackh(v.x), b = unpackh(v.y), c = unpackh(v.z), d = unpackh(v.w);
      s0 += a.x + b.x + c.x + d.x;
      s1 += a.x * a.x + b.x * b.x + c.x * c.x + d.x * d.x;
      s2 += a.y + b.y + c.y + d.y;
      s3 += a.y * a.y + b.y * b.y + c.y * c.y + d.y * d.y;
    }
  }
  s0 = wred64(s0); s1 = wred64(s1); s2 = wred64(s2); s3 = wred64(s3);
  int wave = tid >> 6, lane = tid & 63;
  if (lane == 0) { red[wave][0] = s0; red[wave][1] = s1; red[wave][2] = s2; red[wave][3] = s3; }
  __syncthreads();
  if (tid < 4) {
    double v = (double)red[0][tid] + red[1][tid] + red[2][tid] + red[3][tid];
    if (bid < 96) atomicAdd(&dws[9 + tid], v);
    else { int o = (bid - 96) >> 3; atomicAdd(&dws[16 + tid * 32 + o], v); }
  }
}

__global__ void k_finB(const double* __restrict__ dws, const float* __restrict__ grt, const float* __restrict__ brt,
                       const float* __restrict__ gtt, const float* __restrict__ btt, const float* __restrict__ gmin,
                       const float* __restrict__ bmin, const float* __restrict__ gmax, const float* __restrict__ bmax,
                       const float* __restrict__ gmean, const float* __restrict__ bmean, float* __restrict__ cf) {
  int tid = threadIdx.x;
  if (tid == 32) {
    double m = dws[9] / N1_, v = dws[10] / N1_ - m * m;
    double a = (double)grt[0] / sqrt(v + 1e-5);
    cf[128] = (float)a;
    cf[129] = (float)((double)brt[0] - m * a);
    m = dws[11] / N1_;
    v = dws[12] / N1_ - m * m;
    a = (double)gtt[0] / sqrt(v + 1e-5);
    cf[130] = (float)a;
    cf[131] = (float)((double)btt[0] - m * a);
  }
  if (tid < 32) {
    double m = dws[16 + tid] / N3_, v = dws[48 + tid] / N3_ - m * m;
    double a = (double)gmin[tid] / sqrt(v + 1e-5);
    cf[132 + tid] = (float)a;
    cf[164 + tid] = (float)((double)bmin[tid] - m * a);
    double mm = dws[80 + tid] / N3_, vv = dws[112 + tid] / N3_ - mm * mm;
    a = (double)gmax[tid] / sqrt(vv + 1e-5);
    cf[196 + tid] = (float)a;
    cf[228 + tid] = (float)((double)bmax[tid] - mm * a);
    a = (double)gmean[tid] / sqrt(vv + 1e-5);
    cf[260 + tid] = (float)a;
    cf[292 + tid] = (float)((double)bmean[tid] - mm * a);
  }
}

// passC: read intermediates, assemble enc, write out. No reductions.
__global__ __launch_bounds__(256) void k_passC(const unsigned int* __restrict__ pRT,
                                               const unsigned int* __restrict__ pMM,
                                               const float* __restrict__ wth, const float* __restrict__ bth,
                                               const float* __restrict__ cf, float* __restrict__ out) {
  const int pix = blockIdx.x * 256 + threadIdx.x;
  const int b = pix >> 16, hw = pix & 65535;
  float art = cf[128], brt_ = cf[129], att = cf[130], btt_ = cf[131];
  float rtt[12];
#pragma unroll
  for (int t = 0; t < 12; t++) {
    float2 v = unpackh(pRT[t * NP + pix]);
    rtt[t] = fsilu(fmaf(art, v.x, brt_)) + fsilu(fmaf(att, v.y, btt_));
  }
  float* po = out + (size_t)b * 32 * HW_ + hw;
#pragma unroll
  for (int o = 0; o < 32; o++) {
    float2 mm = unpackh(pMM[o * NP + pix]);
    float tl = bth[o];
#pragma unroll
    for (int t = 0; t < 12; t++) tl = fmaf(wth[o * 12 + t], rtt[t], tl);
    float e = tl + fsilu(fmaf(cf[132 + o], mm.x, cf[164 + o]))
                 + fsilu(fmaf(cf[196 + o], mm.y, cf[228 + o]))
                 + fsilu(fmaf(cf[260 + o], mm.y, cf[292 + o]));
    po[(size_t)o * HW_] = e;
  }
}

// Per-(b,o)-slice sums of enc for instance norm. 4 blocks per slice.
__global__ __launch_bounds__(256) void k_encstats(const float* __restrict__ out, double* __restrict__ dws) {
  __shared__ float red[4][2];
  int s = blockIdx.x >> 2, sub = blockIdx.x & 3, tid = threadIdx.x;
  const float4* p = (const float4*)(out + ((size_t)s << 16));
  float S = 0, SS = 0;
#pragma unroll 4
  for (int it = 0; it < 16; it++) {
    float4 a = p[sub * 256 + tid + it * 1024];
    S += a.x + a.y + a.z + a.w;
    SS += a.x * a.x + a.y * a.y + a.z * a.z + a.w * a.w;
  }
  S = wred64(S); SS = wred64(SS);
  int wave = tid >> 6, lane = tid & 63;
  if (lane == 0) { red[wave][0] = S; red[wave][1] = SS; }
  __syncthreads();
  if (tid < 2) {
    double v = (double)red[0][tid] + red[1][tid] + red[2][tid] + red[3][tid];
    atomicAdd(&dws[160 + 2 * s + tid], v);
  }
}

__global__ __launch_bounds__(256) void k_inorm(const double* __restrict__ dws, float* __restrict__ out) {
  int s = blockIdx.y;
  double S = dws[160 + s * 2], SS = dws[161 + s * 2];
  double m = S / 65536.0, v = SS / 65536.0 - m * m;
  float rstd = (float)(1.0 / sqrt(v + 1e-5));
  float mf = (float)m;
  float4* p = (float4*)(out + ((size_t)s << 16));
  int i = blockIdx.x * 256 + threadIdx.x;
  float4 a = p[i];
  a.x = (a.x - mf) * rstd;
  a.y = (a.y - mf) * rstd;
  a.z = (a.z - mf) * rstd;
  a.w = (a.w - mf) * rstd;
  p[i] = a;
}

extern "C" void kernel_launch(void* const* d_in, const int* in_sizes, int n_in,
                              void* d_out, int out_size, void* d_ws, size_t ws_size,
                              hipStream_t stream) {
  const float* x     = (const float*)d_in[0];
  const float* w0    = (const float*)d_in[1];
  const float* g0    = (const float*)d_in[2];
  const float* b0    = (const float*)d_in[3];
  const float* wrt   = (const float*)d_in[4];
  const float* grt   = (const float*)d_in[5];
  const float* brt   = (const float*)d_in[6];
  const float* wtt   = (const float*)d_in[7];
  const float* gtt   = (const float*)d_in[8];
  const float* btt   = (const float*)d_in[9];
  const float* wth   = (const float*)d_in[10];
  const float* bth   = (const float*)d_in[11];
  const float* gmin  = (const float*)d_in[12];
  const float* bmin  = (const float*)d_in[13];
  const float* gmax  = (const float*)d_in[14];
  const float* bmax  = (const float*)d_in[15];
  const float* gmean = (const float*)d_in[16];
  const float* bmean = (const float*)d_in[17];
  double* dws = (double*)d_ws;
  float* cf = (float*)((char*)d_ws + 4096);
  unsigned int* pRT = (unsigned int*)((char*)d_ws + 8192);
  unsigned int* pMM = pRT + 12 * NP;   // needs ws_size >= ~46.2 MB
  float* out = (float*)d_out;

  hipLaunchKernelGGL(k_init, dim3(2), dim3(256), 0, stream, dws);
  hipLaunchKernelGGL(k_xstats, dim3(768), dim3(256), 0, stream, x, dws);
  hipLaunchKernelGGL(k_fin0, dim3(1), dim3(32), 0, stream, dws, w0, g0, b0, cf);
  hipLaunchKernelGGL(k_passB, dim3(1024), dim3(256), 0, stream, x, wrt, wtt, cf, pRT, pMM);
  hipLaunchKernelGGL(k_stats, dim3(352), dim3(256), 0, stream, pRT, pMM, dws);
  hipLaunchKernelGGL(k_finB, dim3(1), dim3(64), 0, stream, dws, grt, brt, gtt, btt,
                     gmin, bmin, gmax, bmax, gmean, bmean, cf);
  hipLaunchKernelGGL(k_passC, dim3(1024), dim3(256), 0, stream, pRT, pMM, wth, bth, cf, out);
  hipLaunchKernelGGL(k_encstats, dim3(512), dim3(256), 0, stream, out, dws);
  hipLaunchKernelGGL(k_inorm, dim3(64, 128), dim3(256), 0, stream, dws, out);
}